// Round 12
// baseline (394.541 us; speedup 1.0000x reference)
//
#include <hip/hip_runtime.h>
#include <math.h>

#define LATN 721
#define LONN 1440
#define NLEV 13
#define NBATCH 2
#define SLICE (LATN * LONN)              // 1,038,240
#define BATSTRIDE (NLEV * SLICE)

// geometry: thread = 3 output rows x 2 cols (float2); wave = 128 cols, 124 used
#define OUTW 124                         // output cols per wave (lanes 1..62)
#define WGCOLS 496                       // 4 waves
#define SEGS 3                           // ceil(1440/496)
#define NRB 241                          // ceil(721/3) row-blocks (r0 = 3*wgr, last = 720)
#define NWGX (NRB * SEGS)                // 723

// ---- ws float layout ----
#define NBANK      128
#define BANKSTRIDE 64
#define WS_ACC     0                     // [NBANK*BANKSTRIDE]
#define ACC_SUM    0        // [26] per (b,l) sums
#define ACC_SSQ    26       // [2]  per-batch total sum-of-squares
#define ACC_GRAD   28
#define ACC_MASS   29
#define N_ACC      30
#define WS_INVDX   (NBANK * BANKSTRIDE)          // [721]
#define WS_FCOR    (WS_INVDX + LATN)             // [721]
#define WS_W       (WS_FCOR + LATN)              // [13]
#define WS_INVDP   (WS_W + NLEV)
#define WS_INV2DP  (WS_INVDP + 1)

constexpr float INV_R     = (float)(1.0 / 6371000.0);
constexpr float INV_DLAT  = (float)(720.0 / M_PI);
constexpr float INV_2DLAT = (float)(360.0 / M_PI);
constexpr float INV_DLON  = (float)(1440.0 / (2.0 * M_PI));
constexpr float INV_2DLON = (float)(720.0 / (2.0 * M_PI));
constexpr float QG_COEF   = 1e-4f;   // F0^2 / N^2

// ---------------- setup: row tables, weights, zero accumulators ----------------
__global__ void pl_setup_kernel(const float* __restrict__ plev, float* __restrict__ ws) {
    const int t = threadIdx.x;
    if (t < LATN) {
        double lat;
        if (t == 0)            lat = (double)(-(float)(M_PI / 2.0));
        else if (t == LATN-1)  lat = (double)( (float)(M_PI / 2.0));
        else                   lat = (double)((float)(-M_PI / 2.0 + (double)t * (M_PI / 720.0)));
        double c = cos(lat);
        if (c < 1e-8) c = 1e-8;                      // matches jnp.clip(cos, 1e-8)
        ws[WS_INVDX + t] = (float)(1.0 / (6371000.0 * c));
        ws[WS_FCOR  + t] = (float)(2.0 * 7.292e-05 * sin(lat));
    }
    if (t < NLEV) {
        float p[NLEV];
        #pragma unroll
        for (int l = 0; l < NLEV; ++l) p[l] = plev[l] * 100.0f;
        float dpl[NLEV-1];
        #pragma unroll
        for (int l = 0; l < NLEV-1; ++l) dpl[l] = p[l+1] - p[l];
        float raw;
        if (t == 0)            raw = dpl[0] * 0.5f;
        else if (t == NLEV-1)  raw = dpl[NLEV-2] * 0.5f;
        else                   raw = (dpl[t-1] + dpl[t]) * 0.5f;
        float s = dpl[0] * 0.5f + dpl[NLEV-2] * 0.5f;
        #pragma unroll
        for (int l = 1; l < NLEV-1; ++l) s += (dpl[l-1] + dpl[l]) * 0.5f;
        if (s < 1e-8f) s = 1e-8f;
        ws[WS_W + t] = raw / s;
    }
    if (t == 0) {
        float sd = 0.f;
        for (int l = 0; l < NLEV-1; ++l) sd += plev[l+1] - plev[l];
        float dp = sd / (float)(NLEV-1) * 100.0f;    // mean(diff)*100 (hPa->Pa)
        ws[WS_INVDP]  = 1.0f / dp;
        ws[WS_INV2DP] = 1.0f / (2.0f * dp);
    }
    for (int z = t; z < NBANK * BANKSTRIDE; z += 1024) ws[WS_ACC + z] = 0.0f;
}

// ---------------- helpers ----------------
__device__ __forceinline__ int swz_nwg(int orig, int nwg) {
    // bijective XCD-chunk swizzle (m204)
    const int q = nwg >> 3, r = nwg & 7;
    const int x = orig & 7, k = orig >> 3;
    return (x < r ? x * (q + 1) : r * (q + 1) + (x - r) * q) + k;
}
__device__ __forceinline__ float2 ld2(const float* p) {
    return *reinterpret_cast<const float2*>(p);
}
__device__ __forceinline__ float2 sm2(float2 a, float2 b, float s) {   // (a-b)*s
    return make_float2((a.x - b.x) * s, (a.y - b.y) * s);
}

// ---------------- fused kernel: 3 rows x 2 cols per thread, 5 rolling qg streams ----------------
// (256,4): VGPR cap 128 — R11 lesson: uncapped, the unrolled level loop's load
// hoisting runs to 256 VGPR + 175 MB scratch. Cap prunes hoist depth instead.
__launch_bounds__(256, 4)
__global__ void pl_rc32_kernel(const float* __restrict__ u, const float* __restrict__ v,
                               float* __restrict__ ws)
{
    __shared__ float red[16][17];

    const int tid  = threadIdx.x;
    const int lane = tid & 63, w = tid >> 6;
    const int b  = blockIdx.y;
    const int wg = swz_nwg(blockIdx.x, NWGX);
    const int wgr = wg / SEGS, seg = wg - wgr * SEGS;
    const int r0  = 3 * wgr;                         // 0,3,...,720

    // columns: lane owns pair (c0, c0+1); lanes 1..62 are outputs, 0/63 shfl halo
    const int out0  = seg * WGCOLS + w * OUTW;
    const int c0_un = out0 - 2 + 2 * lane;           // even
    const int cb = max(0, min(c0_un, LONN - 2));     // 8B-aligned pair base
    const float m0 = (lane >= 1 && lane <= 62 && c0_un     < LONN) ? 1.f : 0.f;
    const float m1 = (lane >= 1 && lane <= 62 && c0_un + 1 < LONN) ? 1.f : 0.f;
    const bool e0 = (c0_un == 0);                    // .x is col 0 (parity: always .x)
    const bool e1 = (c0_un + 1 == LONN - 1);         // .y is col 1439 (always .y)

    // rows: outputs r0..r0+2; vort streams j=0..4 = rows r0-1..r0+3
    const bool rTop = (r0 == 0), rBot = (r0 == LATN - 1);   // r0==720 only at wgr=240
    const float rv1 = (r0 + 1 < LATN) ? 1.f : 0.f;
    const float rv2 = (r0 + 2 < LATN) ? 1.f : 0.f;
    const float m10 = m0 * rv1, m11 = m1 * rv1;
    const float m20 = m0 * rv2, m21 = m1 * rv2;

    // clamped global rows: u streams k=0..6 (r0-2+k), v/vort streams j=0..4 (r0-1+j)
    #define CR(x) max(0, min((x), LATN - 1))
    const int gv0 = CR(r0 - 1), gv1 = r0,        gv2 = CR(r0 + 1);
    const int gv3 = CR(r0 + 2), gv4 = CR(r0 + 3);
    const int ou0 = CR(r0 - 2) * LONN + cb, ou1 = gv0 * LONN + cb;
    const int ou2 = r0 * LONN + cb,         ou3 = gv2 * LONN + cb;
    const int ou4 = gv3 * LONN + cb,        ou5 = gv4 * LONN + cb;
    const int ou6 = CR(r0 + 4) * LONN + cb;
    const int ov0 = ou1, ov1 = ou2, ov2 = ou3, ov3 = ou4, ov4 = ou5;
    #undef CR

    const float* pu = u + (size_t)b * BATSTRIDE;
    const float* pv = v + (size_t)b * BATSTRIDE;
    const float idp = ws[WS_INVDP], i2dp = ws[WS_INV2DP];

    // per-vort-row scales (WG-uniform except eC0/eC1 lane factor)
    const float eC0 = e0 ? INV_DLON : INV_2DLON;
    const float eC1 = e1 ? INV_DLON : INV_2DLON;
    #define SRV(g) ((((g) == 0) || ((g) == LATN - 1)) ? INV_DLAT * INV_R : INV_2DLAT * INV_R)
    const float srv0 = SRV(gv0), srv1 = SRV(gv1), srv2 = SRV(gv2);
    const float srv3 = SRV(gv3), srv4 = SRV(gv4);
    #undef SRV
    const float ix0 = ws[WS_INVDX + gv0], ix1 = ws[WS_INVDX + gv1];
    const float ix2 = ws[WS_INVDX + gv2], ix3 = ws[WS_INVDX + gv3];
    const float ix4 = ws[WS_INVDX + gv4];
    const float fc0 = ws[WS_FCOR + gv0], fc1 = ws[WS_FCOR + gv1];
    const float fc2 = ws[WS_FCOR + gv2], fc3 = ws[WS_FCOR + gv3];
    const float fc4 = ws[WS_FCOR + gv4];

    float vals[16];
    #pragma unroll
    for (int k = 0; k < 16; ++k) vals[k] = 0.f;
    float ssqt = 0.f, grad = 0.f;
    float2 wu0 = {0.f,0.f}, wu1 = {0.f,0.f}, wu2 = {0.f,0.f};
    float2 wv0 = {0.f,0.f}, wv1 = {0.f,0.f}, wv2 = {0.f,0.f};
    float2 wv3 = {0.f,0.f}, wv4 = {0.f,0.f};

    auto qgf = [&](float2 vo, float fc, float2 vpp) -> float2 {
        return make_float2(vo.x + fc + QG_COEF * vpp.x, vo.y + fc + QG_COEF * vpp.y);
    };
    auto vortf = [&](float2 vv, float2 ulo, float2 uhi, float ix, float sr) -> float2 {
        const float vL = __shfl_up(vv.y, 1), vR = __shfl_down(vv.x, 1);
        float2 r_;
        r_.x = (vv.y - (e0 ? vv.x : vL)) * (eC0 * ix) - (uhi.x - ulo.x) * sr;
        r_.y = ((e1 ? vv.y : vR) - vv.x) * (eC1 * ix) - (uhi.y - ulo.y) * sr;
        return r_;
    };
    // one output row: qm/qc/qp = qg of streams i, i+1, i+2; scale row = stream i+1
    auto crow = [&](int k, float2 qm, float2 qc, float2 qp,
                    float sr, float ix, float mk0, float mk1) {
        const float qx = qc.x * mk0, qy = qc.y * mk1;
        vals[k] += qx + qy;
        ssqt += qx * qx + qy * qy;
        const float2 gl = sm2(qp, qm, sr);
        const float qL = __shfl_up(qc.y, 1), qR = __shfl_down(qc.x, 1);
        const float gnx = (qc.y - (e0 ? qc.x : qL)) * (eC0 * ix);
        const float gny = ((e1 ? qc.y : qR) - qc.x) * (eC1 * ix);
        grad += mk0 * (gl.x * gl.x + gnx * gnx) + mk1 * (gl.y * gl.y + gny * gny);
    };

    // rolling state ONLY (R8/R11 lesson: NO level-indexed arrays)
    float2 vo2_0, vo1_0, pa_0, pb_0;
    float2 vo2_1, vo1_1, pa_1, pb_1;
    float2 vo2_2, vo1_2, pa_2, pb_2;
    float2 vo2_3, vo1_3, pa_3, pb_3;
    float2 vo2_4, vo1_4, pa_4, pb_4;

    #define PIPE(S, CO, FC, QOUT) do {                                           \
        if (l == 0) { vo1_##S = (CO); }                                          \
        else if (l == 1) {                                                       \
            pb_##S = sm2((CO), vo1_##S, idp);                                    \
            vo2_##S = vo1_##S; vo1_##S = (CO);                                   \
        } else {                                                                 \
            const float2 pn_ = sm2((CO), vo2_##S, i2dp);                         \
            QOUT = (l == 2) ? qgf(vo2_##S, (FC), sm2(pn_, pb_##S, idp))          \
                            : qgf(vo2_##S, (FC), sm2(pn_, pa_##S, i2dp));        \
            pa_##S = pb_##S; pb_##S = pn_;                                       \
            vo2_##S = vo1_##S; vo1_##S = (CO);                                   \
        }                                                                        \
    } while (0)

    #pragma unroll
    for (int l = 0; l < NLEV; ++l) {
        const float wl = ws[WS_W + l];               // uniform -> SGPR
        const float2 u0 = ld2(pu + ou0), u1 = ld2(pu + ou1), u2 = ld2(pu + ou2);
        const float2 u3 = ld2(pu + ou3), u4 = ld2(pu + ou4), u5 = ld2(pu + ou5);
        const float2 u6 = ld2(pu + ou6);
        const float2 v0 = ld2(pv + ov0), v1 = ld2(pv + ov1), v2 = ld2(pv + ov2);
        const float2 v3 = ld2(pv + ov3), v4 = ld2(pv + ov4);

        wu0.x = fmaf(wl, u2.x, wu0.x);  wu0.y = fmaf(wl, u2.y, wu0.y);
        wu1.x = fmaf(wl, u3.x, wu1.x);  wu1.y = fmaf(wl, u3.y, wu1.y);
        wu2.x = fmaf(wl, u4.x, wu2.x);  wu2.y = fmaf(wl, u4.y, wu2.y);
        wv0.x = fmaf(wl, v0.x, wv0.x);  wv0.y = fmaf(wl, v0.y, wv0.y);
        wv1.x = fmaf(wl, v1.x, wv1.x);  wv1.y = fmaf(wl, v1.y, wv1.y);
        wv2.x = fmaf(wl, v2.x, wv2.x);  wv2.y = fmaf(wl, v2.y, wv2.y);
        wv3.x = fmaf(wl, v3.x, wv3.x);  wv3.y = fmaf(wl, v3.y, wv3.y);
        wv4.x = fmaf(wl, v4.x, wv4.x);  wv4.y = fmaf(wl, v4.y, wv4.y);

        // vort stream j uses v_j and u_j, u_{j+2}; clamped edge loads + one-sided
        // sr are EXACT for real edge rows; only nonexistent rows need selects
        float2 co0 = vortf(v0, u0, u2, ix0, srv0);
        const float2 co1 = vortf(v1, u1, u3, ix1, srv1);
        float2 co2 = vortf(v2, u2, u4, ix2, srv2);
        float2 co3 = vortf(v3, u3, u5, ix3, srv3);
        float2 co4 = vortf(v4, u4, u6, ix4, srv4);
        if (rTop) co0 = co1;                         // row -1 -> row 0's stream
        if (rBot) { co2 = co1; co3 = co1; co4 = co1; }   // rows 721+ -> row 720's

        float2 q0, q1, q2, q3, q4;
        PIPE(0, co0, fc0, q0);  PIPE(1, co1, fc1, q1);  PIPE(2, co2, fc2, q2);
        PIPE(3, co3, fc3, q3);  PIPE(4, co4, fc4, q4);
        if (l >= 2) {
            crow(l - 2, q0, q1, q2, srv1, ix1, m0,  m1);
            crow(l - 2, q1, q2, q3, srv2, ix2, m10, m11);
            crow(l - 2, q2, q3, q4, srv3, ix3, m20, m21);
        }
        pu += SLICE; pv += SLICE;                    // uniform SALU bump
    }
    #undef PIPE
    // tail: vp1[12] one-sided; emit qg[11], qg[12]
    {
        #define TAIL(S, FC, Q11, Q12) do {                                       \
            const float2 p12_ = sm2(vo1_##S, vo2_##S, idp);                      \
            Q11 = qgf(vo2_##S, (FC), sm2(p12_, pa_##S, i2dp));                   \
            Q12 = qgf(vo1_##S, (FC), sm2(p12_, pb_##S, idp));                    \
        } while (0)
        float2 a0, b0, a1, b1, a2, b2, a3, b3, a4, b4;
        TAIL(0, fc0, a0, b0);  TAIL(1, fc1, a1, b1);  TAIL(2, fc2, a2, b2);
        TAIL(3, fc3, a3, b3);  TAIL(4, fc4, a4, b4);
        #undef TAIL
        crow(11, a0, a1, a2, srv1, ix1, m0,  m1);
        crow(11, a1, a2, a3, srv2, ix2, m10, m11);
        crow(11, a2, a3, a4, srv3, ix3, m20, m21);
        crow(12, b0, b1, b2, srv1, ix1, m0,  m1);
        crow(12, b1, b2, b3, srv2, ix2, m10, m11);
        crow(12, b2, b3, b4, srv3, ix3, m20, m21);
    }

    vals[13] += ssqt;
    vals[14] += grad;
    // mass: du/dx in-lane/shfl + edge selects; dv/dy via wv streams (clamped -> exact edges)
    {
        #define MROW(WU, WVLO, WVHI, SR, IX, MK0, MK1) do {                      \
            const float uL = __shfl_up((WU).y, 1), uR = __shfl_down((WU).x, 1);  \
            const float cdx = ((WU).y - (e0 ? (WU).x : uL)) * (eC0 * (IX))       \
                            + ((WVHI).x - (WVLO).x) * (SR);                      \
            const float cdy = ((e1 ? (WU).y : uR) - (WU).x) * (eC1 * (IX))       \
                            + ((WVHI).y - (WVLO).y) * (SR);                      \
            vals[15] += (MK0) * cdx * cdx + (MK1) * cdy * cdy;                   \
        } while (0)
        MROW(wu0, wv0, wv2, srv1, ix1, m0,  m1);
        MROW(wu1, wv1, wv3, srv2, ix2, m10, m11);
        MROW(wu2, wv2, wv4, srv3, ix3, m20, m21);
        #undef MROW
    }

    // ---- reduction: 4-step 16-lane-group butterfly + LDS transpose (16 values) ----
    #pragma unroll
    for (int k = 0; k < 16; ++k) {
        float x = vals[k];
        x += __shfl_xor(x, 8, 64);
        x += __shfl_xor(x, 4, 64);
        x += __shfl_xor(x, 2, 64);
        x += __shfl_xor(x, 1, 64);
        vals[k] = x;
    }
    const int g = tid >> 4, k16 = tid & 15;
    float myv = vals[0];
    #pragma unroll
    for (int k = 1; k < 16; ++k) if (k16 == k) myv = vals[k];   // static-index select
    red[g][k16] = myv;
    __syncthreads();

    if (tid < 16) {
        const int k = tid;
        float s = 0.f;
        #pragma unroll
        for (int g2 = 0; g2 < 16; ++g2) s += red[g2][k];
        int target;
        if (k < 13)       target = ACC_SUM + b * 13 + k;
        else if (k == 13) target = ACC_SSQ + b;
        else if (k == 14) target = ACC_GRAD;
        else              target = ACC_MASS;
        const int bank = (b * NWGX + blockIdx.x) & (NBANK - 1);
        atomicAdd(&ws[WS_ACC + bank * BANKSTRIDE + target], s);
    }
}

// ---------------- finalize: sum banks, apply formulas ----------------
__global__ void pl_finalize_kernel(const float* __restrict__ ws, float* __restrict__ out) {
    __shared__ float tot[N_ACC];
    const int t = threadIdx.x;
    if (t < N_ACC) {
        float s = 0.f;
        for (int bk = 0; bk < NBANK; ++bk) s += ws[WS_ACC + bk * BANKSTRIDE + t];
        tot[t] = s;
    }
    __syncthreads();
    if (t == 0) {
        const float N = (float)SLICE;
        float s2 = 0.f;
        for (int s = 0; s < 2 * NLEV; ++s) s2 += tot[ACC_SUM + s] * tot[ACC_SUM + s];
        const float ssq = tot[ACC_SSQ + 0] + tot[ACC_SSQ + 1];
        float vmean = (ssq - s2 / N) / (N - 1.0f) * (1.0f / (2.0f * NLEV));
        float gmean = tot[ACC_GRAD] / (float)(NBATCH * NLEV * SLICE);
        float mmean = tot[ACC_MASS] / (float)(NBATCH * SLICE);
        out[0] = vmean + 0.1f * gmean + mmean;          // spectra_loss statically 0
    }
}

extern "C" void kernel_launch(void* const* d_in, const int* in_sizes, int n_in,
                              void* d_out, int out_size, void* d_ws, size_t ws_size,
                              hipStream_t stream) {
    const float* u    = (const float*)d_in[0];
    const float* v    = (const float*)d_in[1];
    const float* plev = (const float*)d_in[2];
    float* ws  = (float*)d_ws;
    float* out = (float*)d_out;

    hipLaunchKernelGGL(pl_setup_kernel, dim3(1), dim3(1024), 0, stream, plev, ws);
    hipLaunchKernelGGL(pl_rc32_kernel, dim3(NWGX, NBATCH), dim3(256), 0, stream, u, v, ws);
    hipLaunchKernelGGL(pl_finalize_kernel, dim3(1), dim3(64), 0, stream, ws, out);
}

// Round 13
// 54.111 us; speedup vs baseline: 7.2914x; 7.2914x over previous
//
#include <hip/hip_runtime.h>
#include <math.h>

#define LATN 721
#define LONN 1440
#define NLEV 13
#define NBATCH 2
#define SLICE (LATN * LONN)              // 1,038,240
#define BATSTRIDE (NLEV * SLICE)

// geometry: thread = 2 output rows x 2 cols (float2); wave = 128 cols, 124 outputs
#define OUTW 124                         // outputs per wave (lanes 1..62, 2 cols each)
#define WGCOLS 496                       // 4 waves
#define SEGS 3                           // ceil(1440/496)
#define NROWP 361                        // ceil(721/2) row-pairs
#define NWGX (NROWP * SEGS)              // 1083

// ---- ws float layout ----
#define NBANK      128
#define BANKSTRIDE 64
#define WS_ACC     0                     // [NBANK*BANKSTRIDE]
#define ACC_SUM    0        // [26] per (b,l) sums
#define ACC_SSQ    26       // [2]  per-batch total sum-of-squares
#define ACC_GRAD   28
#define ACC_MASS   29
#define N_ACC      30
#define WS_INVDX   (NBANK * BANKSTRIDE)          // [721]
#define WS_FCOR    (WS_INVDX + LATN)             // [721]
#define WS_W       (WS_FCOR + LATN)              // [13]
#define WS_INVDP   (WS_W + NLEV)
#define WS_INV2DP  (WS_INVDP + 1)

constexpr float INV_R     = (float)(1.0 / 6371000.0);
constexpr float INV_DLAT  = (float)(720.0 / M_PI);
constexpr float INV_2DLAT = (float)(360.0 / M_PI);
constexpr float INV_DLON  = (float)(1440.0 / (2.0 * M_PI));
constexpr float INV_2DLON = (float)(720.0 / (2.0 * M_PI));
constexpr float QG_COEF   = 1e-4f;   // F0^2 / N^2

// ---------------- setup: row tables, weights, zero accumulators ----------------
__global__ void pl_setup_kernel(const float* __restrict__ plev, float* __restrict__ ws) {
    const int t = threadIdx.x;
    if (t < LATN) {
        double lat;
        if (t == 0)            lat = (double)(-(float)(M_PI / 2.0));
        else if (t == LATN-1)  lat = (double)( (float)(M_PI / 2.0));
        else                   lat = (double)((float)(-M_PI / 2.0 + (double)t * (M_PI / 720.0)));
        double c = cos(lat);
        if (c < 1e-8) c = 1e-8;                      // matches jnp.clip(cos, 1e-8)
        ws[WS_INVDX + t] = (float)(1.0 / (6371000.0 * c));
        ws[WS_FCOR  + t] = (float)(2.0 * 7.292e-05 * sin(lat));
    }
    if (t < NLEV) {
        float p[NLEV];
        #pragma unroll
        for (int l = 0; l < NLEV; ++l) p[l] = plev[l] * 100.0f;
        float dpl[NLEV-1];
        #pragma unroll
        for (int l = 0; l < NLEV-1; ++l) dpl[l] = p[l+1] - p[l];
        float raw;
        if (t == 0)            raw = dpl[0] * 0.5f;
        else if (t == NLEV-1)  raw = dpl[NLEV-2] * 0.5f;
        else                   raw = (dpl[t-1] + dpl[t]) * 0.5f;
        float s = dpl[0] * 0.5f + dpl[NLEV-2] * 0.5f;
        #pragma unroll
        for (int l = 1; l < NLEV-1; ++l) s += (dpl[l-1] + dpl[l]) * 0.5f;
        if (s < 1e-8f) s = 1e-8f;
        ws[WS_W + t] = raw / s;
    }
    if (t == 0) {
        float sd = 0.f;
        for (int l = 0; l < NLEV-1; ++l) sd += plev[l+1] - plev[l];
        float dp = sd / (float)(NLEV-1) * 100.0f;    // mean(diff)*100 (hPa->Pa)
        ws[WS_INVDP]  = 1.0f / dp;
        ws[WS_INV2DP] = 1.0f / (2.0f * dp);
    }
    for (int z = t; z < NBANK * BANKSTRIDE; z += 1024) ws[WS_ACC + z] = 0.0f;
}

// ---------------- helpers ----------------
__device__ __forceinline__ int swz_nwg(int orig, int nwg) {
    // bijective XCD-chunk swizzle (m204)
    const int q = nwg >> 3, r = nwg & 7;
    const int x = orig & 7, k = orig >> 3;
    return (x < r ? x * (q + 1) : r * (q + 1) + (x - r) * q) + k;
}
__device__ __forceinline__ float2 ld2(const float* p) {
    return *reinterpret_cast<const float2*>(p);
}
__device__ __forceinline__ float2 sm2(float2 a, float2 b, float s) {   // (a-b)*s
    return make_float2((a.x - b.x) * s, (a.y - b.y) * s);
}

// ---------------- fused kernel: R10 structure + 1-level software-prefetch dbuf ----------------
// Plain (256): R2/R12 showed min-waves hints misfire. Named a/b buffers + per-level
// sched_barrier bound the compiler's load hoisting to exactly 1 level (R11 lesson).
__launch_bounds__(256)
__global__ void pl_rc22p_kernel(const float* __restrict__ u, const float* __restrict__ v,
                                float* __restrict__ ws)
{
    __shared__ float red[16][17];

    const int tid  = threadIdx.x;
    const int lane = tid & 63, w = tid >> 6;
    const int b  = blockIdx.y;
    const int wg = swz_nwg(blockIdx.x, NWGX);
    const int wgr = wg / SEGS, seg = wg - wgr * SEGS;
    const int r0  = 2 * wgr;                         // 0,2,...,720

    // columns: lane owns pair (c0, c0+1); lanes 1..62 are outputs, 0/63 shfl halo
    const int out0  = seg * WGCOLS + w * OUTW;
    const int c0_un = out0 - 2 + 2 * lane;           // even
    const int cb = max(0, min(c0_un, LONN - 2));     // 8B-aligned pair base
    const float m0 = (lane >= 1 && lane <= 62 && c0_un     < LONN) ? 1.f : 0.f;
    const float m1 = (lane >= 1 && lane <= 62 && c0_un + 1 < LONN) ? 1.f : 0.f;
    const bool e0 = (c0_un == 0);                    // .x is col 0 (parity: always .x)
    const bool e1 = (c0_un + 1 == LONN - 1);         // .y is col 1439 (always .y)

    // rows: outputs r0 (a), r0+1 (b); vort rows m=r0-1, a, b, p=r0+2
    const bool rTop = (r0 == 0), rBotA = (r0 == LATN - 1);
    const float rbf = (r0 + 1 < LATN) ? 1.f : 0.f;
    const float mb0 = m0 * rbf, mb1 = m1 * rbf;
    const int crm = max(r0 - 1, 0);
    const int crb = min(r0 + 1, LATN - 1);
    const int crp = min(r0 + 2, LATN - 1);
    const int cu0 = max(r0 - 2, 0), cu1 = crm, cu2 = r0;
    const int cu3 = crb, cu4 = crp, cu5 = min(r0 + 3, LATN - 1);

    const float idp = ws[WS_INVDP], i2dp = ws[WS_INV2DP];

    // scales: eC0/eC1 fold per-column one-sided factor
    const float eC0 = e0 ? INV_DLON : INV_2DLON;
    const float eC1 = e1 ? INV_DLON : INV_2DLON;
    const float ixm = ws[WS_INVDX + crm], ixa = ws[WS_INVDX + r0];
    const float ixb = ws[WS_INVDX + crb], ixp = ws[WS_INVDX + crp];
    const float sm0 = eC0 * ixm, sm1 = eC1 * ixm;
    const float sa0 = eC0 * ixa, sa1 = eC1 * ixa;
    const float sb0 = eC0 * ixb, sb1 = eC1 * ixb;
    const float sp0 = eC0 * ixp, sp1 = eC1 * ixp;
    const float sr_a = ((rTop || rBotA) ? INV_DLAT : INV_2DLAT) * INV_R;
    const float sr_mb = INV_2DLAT * INV_R;           // rows m/b never grid-edge (parity)
    const float sr_p = ((r0 + 2 >= LATN - 1) ? INV_DLAT : INV_2DLAT) * INV_R;
    const float fc_m = ws[WS_FCOR + crm], fc_a = ws[WS_FCOR + r0];
    const float fc_b = ws[WS_FCOR + crb], fc_p = ws[WS_FCOR + crp];

    // element offsets (pair base); level advance = uniform SGPR pointer bump
    const int o_u0 = cu0 * LONN + cb, o_u1 = cu1 * LONN + cb, o_u2 = cu2 * LONN + cb;
    const int o_u3 = cu3 * LONN + cb, o_u4 = cu4 * LONN + cb, o_u5 = cu5 * LONN + cb;
    const int o_vm = crm * LONN + cb, o_va = r0 * LONN + cb;
    const int o_vb = crb * LONN + cb, o_vp = crp * LONN + cb;

    // level weights preloaded (static index after unroll -> SGPRs; keeps pinned
    // iterations free of SMEM latency)
    float wlev[NLEV];
    #pragma unroll
    for (int l = 0; l < NLEV; ++l) wlev[l] = ws[WS_W + l];

    float vals[16];
    #pragma unroll
    for (int k = 0; k < 16; ++k) vals[k] = 0.f;
    float ssqt = 0.f, grad = 0.f;
    float2 wu_a = make_float2(0.f, 0.f), wu_b = make_float2(0.f, 0.f);
    float2 wvm = make_float2(0.f, 0.f), wva = make_float2(0.f, 0.f);
    float2 wvb = make_float2(0.f, 0.f), wvp = make_float2(0.f, 0.f);

    auto qgf = [&](float2 vo, float fc, float2 vpp) -> float2 {
        return make_float2(vo.x + fc + QG_COEF * vpp.x, vo.y + fc + QG_COEF * vpp.y);
    };
    auto consume = [&](int k, float2 qm, float2 qa, float2 qb, float2 qp) {
        const float qax = qa.x * m0,  qay = qa.y * m1;
        const float qbx = qb.x * mb0, qby = qb.y * mb1;
        vals[k] += (qax + qay) + (qbx + qby);
        ssqt += qax * qax + qay * qay + qbx * qbx + qby * qby;
        const float2 gla = sm2(qb, qm, sr_a);        // row clamps folded via vo selects
        const float2 glb = sm2(qp, qa, sr_mb);
        const float qaL = __shfl_up(qa.y, 1), qaR = __shfl_down(qa.x, 1);
        const float qbL = __shfl_up(qb.y, 1), qbR = __shfl_down(qb.x, 1);
        const float gnax = (qa.y - (e0 ? qa.x : qaL)) * sa0;
        const float gnay = ((e1 ? qa.y : qaR) - qa.x) * sa1;
        const float gnbx = (qb.y - (e0 ? qb.x : qbL)) * sb0;
        const float gnby = ((e1 ? qb.y : qbR) - qb.x) * sb1;
        grad += m0  * (gla.x * gla.x + gnax * gnax) + m1  * (gla.y * gla.y + gnay * gnay)
              + mb0 * (glb.x * glb.x + gnbx * gnbx) + mb1 * (glb.y * glb.y + gnby * gnby);
    };

    // rolling state ONLY (R8/R11 lesson: NO level-indexed arrays)
    float2 vo2_m, vo1_m, pa_m, pb_m;
    float2 vo2_a, vo1_a, pa_a, pb_a;
    float2 vo2_b, vo1_b, pa_b, pb_b;
    float2 vo2_p, vo1_p, pa_p, pb_p;

    // named double-buffer registers (a / b) — statically swapped via even/odd unroll
    float2 u0a, u1a, u2a, u3a, u4a, u5a, vma, vaa, vba, vpa;
    float2 u0b, u1b, u2b, u3b, u4b, u5b, vmb, vab, vbb, vpb;

    const float* pu = u + (size_t)b * BATSTRIDE;
    const float* pv = v + (size_t)b * BATSTRIDE;

    #define LOADSET(S) do {                                                     \
        u0##S = ld2(pu + o_u0); u1##S = ld2(pu + o_u1); u2##S = ld2(pu + o_u2); \
        u3##S = ld2(pu + o_u3); u4##S = ld2(pu + o_u4); u5##S = ld2(pu + o_u5); \
        vm##S = ld2(pv + o_vm); va##S = ld2(pv + o_va);                         \
        vb##S = ld2(pv + o_vb); vp##S = ld2(pv + o_vp);                         \
        pu += SLICE; pv += SLICE;                                               \
    } while (0)

    // COMPUTE(L, S): R10's level body verbatim on buffer S (math order identical)
    #define COMPUTE(L, S) do {                                                            \
        const float wl = wlev[(L)];                                                       \
        wu_a.x = fmaf(wl, u2##S.x, wu_a.x);  wu_a.y = fmaf(wl, u2##S.y, wu_a.y);          \
        wu_b.x = fmaf(wl, u3##S.x, wu_b.x);  wu_b.y = fmaf(wl, u3##S.y, wu_b.y);          \
        wvm.x = fmaf(wl, vm##S.x, wvm.x);    wvm.y = fmaf(wl, vm##S.y, wvm.y);            \
        wva.x = fmaf(wl, va##S.x, wva.x);    wva.y = fmaf(wl, va##S.y, wva.y);            \
        wvb.x = fmaf(wl, vb##S.x, wvb.x);    wvb.y = fmaf(wl, vb##S.y, wvb.y);            \
        wvp.x = fmaf(wl, vp##S.x, wvp.x);    wvp.y = fmaf(wl, vp##S.y, wvp.y);            \
        const float vmL_ = __shfl_up(vm##S.y, 1),  vmR_ = __shfl_down(vm##S.x, 1);        \
        const float vaL_ = __shfl_up(va##S.y, 1),  vaR_ = __shfl_down(va##S.x, 1);        \
        const float vbL_ = __shfl_up(vb##S.y, 1),  vbR_ = __shfl_down(vb##S.x, 1);        \
        const float vpL_ = __shfl_up(vp##S.y, 1),  vpR_ = __shfl_down(vp##S.x, 1);        \
        float2 com, coa, cob, cop;                                                        \
        com.x = (vm##S.y - (e0 ? vm##S.x : vmL_)) * sm0 - (u2##S.x - u0##S.x) * sr_mb;    \
        com.y = ((e1 ? vm##S.y : vmR_) - vm##S.x) * sm1 - (u2##S.y - u0##S.y) * sr_mb;    \
        coa.x = (va##S.y - (e0 ? va##S.x : vaL_)) * sa0 - (u3##S.x - u1##S.x) * sr_a;     \
        coa.y = ((e1 ? va##S.y : vaR_) - va##S.x) * sa1 - (u3##S.y - u1##S.y) * sr_a;     \
        cob.x = (vb##S.y - (e0 ? vb##S.x : vbL_)) * sb0 - (u4##S.x - u2##S.x) * sr_mb;    \
        cob.y = ((e1 ? vb##S.y : vbR_) - vb##S.x) * sb1 - (u4##S.y - u2##S.y) * sr_mb;    \
        cop.x = (vp##S.y - (e0 ? vp##S.x : vpL_)) * sp0 - (u5##S.x - u3##S.x) * sr_p;     \
        cop.y = ((e1 ? vp##S.y : vpR_) - vp##S.x) * sp1 - (u5##S.y - u3##S.y) * sr_p;     \
        if (rTop)  com = coa;                        /* clamped halo row == own row */    \
        if (rBotA) { cob = coa; cop = coa; }                                              \
        if ((L) == 0) {                                                                   \
            vo1_m = com; vo1_a = coa; vo1_b = cob; vo1_p = cop;                           \
        } else if ((L) == 1) {                                                            \
            pb_m = sm2(com, vo1_m, idp);  pb_a = sm2(coa, vo1_a, idp);                    \
            pb_b = sm2(cob, vo1_b, idp);  pb_p = sm2(cop, vo1_p, idp);                    \
            vo2_m = vo1_m; vo1_m = com;   vo2_a = vo1_a; vo1_a = coa;                     \
            vo2_b = vo1_b; vo1_b = cob;   vo2_p = vo1_p; vo1_p = cop;                     \
        } else {                                                                          \
            const float2 pn_m = sm2(com, vo2_m, i2dp);   /* vp1[l-1] */                   \
            const float2 pn_a = sm2(coa, vo2_a, i2dp);                                    \
            const float2 pn_b = sm2(cob, vo2_b, i2dp);                                    \
            const float2 pn_p = sm2(cop, vo2_p, i2dp);                                    \
            float2 qm, qa, qb, qp;                                                        \
            if ((L) == 2) {                                                               \
                qm = qgf(vo2_m, fc_m, sm2(pn_m, pb_m, idp));                              \
                qa = qgf(vo2_a, fc_a, sm2(pn_a, pb_a, idp));                              \
                qb = qgf(vo2_b, fc_b, sm2(pn_b, pb_b, idp));                              \
                qp = qgf(vo2_p, fc_p, sm2(pn_p, pb_p, idp));                              \
            } else {                                                                      \
                qm = qgf(vo2_m, fc_m, sm2(pn_m, pa_m, i2dp));                             \
                qa = qgf(vo2_a, fc_a, sm2(pn_a, pa_a, i2dp));                             \
                qb = qgf(vo2_b, fc_b, sm2(pn_b, pa_b, i2dp));                             \
                qp = qgf(vo2_p, fc_p, sm2(pn_p, pa_p, i2dp));                             \
            }                                                                             \
            consume((L) - 2, qm, qa, qb, qp);                                             \
            pa_m = pb_m; pb_m = pn_m;  vo2_m = vo1_m; vo1_m = com;                        \
            pa_a = pb_a; pb_a = pn_a;  vo2_a = vo1_a; vo1_a = coa;                        \
            pa_b = pb_b; pb_b = pn_b;  vo2_b = vo1_b; vo1_b = cob;                        \
            pa_p = pb_p; pb_p = pn_p;  vo2_p = vo1_p; vo1_p = cop;                        \
        }                                                                                 \
    } while (0)

    // ---- level loop: prefetch(l+1) issued BEFORE compute(l); 10 loads always in flight ----
    LOADSET(a);                                   // level 0
    #pragma unroll
    for (int l = 0; l < NLEV; ++l) {
        if ((l & 1) == 0) {
            if (l + 1 < NLEV) LOADSET(b);
            COMPUTE(l, a);
        } else {
            if (l + 1 < NLEV) LOADSET(a);
            COMPUTE(l, b);
        }
        __builtin_amdgcn_sched_barrier(0);        // bound hoisting to 1 level (R11 lesson)
    }
    #undef LOADSET
    #undef COMPUTE

    // tail: vp1[12] one-sided; emit qg[11], qg[12]
    {
        const float2 p12m = sm2(vo1_m, vo2_m, idp);
        const float2 p12a = sm2(vo1_a, vo2_a, idp);
        const float2 p12b = sm2(vo1_b, vo2_b, idp);
        const float2 p12p = sm2(vo1_p, vo2_p, idp);
        consume(11, qgf(vo2_m, fc_m, sm2(p12m, pa_m, i2dp)),
                    qgf(vo2_a, fc_a, sm2(p12a, pa_a, i2dp)),
                    qgf(vo2_b, fc_b, sm2(p12b, pa_b, i2dp)),
                    qgf(vo2_p, fc_p, sm2(p12p, pa_p, i2dp)));
        consume(12, qgf(vo1_m, fc_m, sm2(p12m, pb_m, idp)),
                    qgf(vo1_a, fc_a, sm2(p12a, pb_a, idp)),
                    qgf(vo1_b, fc_b, sm2(p12b, pb_b, idp)),
                    qgf(vo1_p, fc_p, sm2(p12p, pb_p, idp)));
    }

    vals[13] += ssqt;
    vals[14] += grad;
    // mass: du/dx in-lane/shfl + edge selects; dv/dy in-thread (clamped loads -> exact edges)
    {
        const float waL = __shfl_up(wu_a.y, 1), waR = __shfl_down(wu_a.x, 1);
        const float wbL = __shfl_up(wu_b.y, 1), wbR = __shfl_down(wu_b.x, 1);
        const float cdax = (wu_a.y - (e0 ? wu_a.x : waL)) * sa0 + (wvb.x - wvm.x) * sr_a;
        const float cday = ((e1 ? wu_a.y : waR) - wu_a.x) * sa1 + (wvb.y - wvm.y) * sr_a;
        const float cdbx = (wu_b.y - (e0 ? wu_b.x : wbL)) * sb0 + (wvp.x - wva.x) * sr_mb;
        const float cdby = ((e1 ? wu_b.y : wbR) - wu_b.x) * sb1 + (wvp.y - wva.y) * sr_mb;
        vals[15] += m0 * cdax * cdax + m1 * cday * cday
                  + mb0 * cdbx * cdbx + mb1 * cdby * cdby;
    }

    // ---- reduction: 4-step 16-lane-group butterfly + LDS transpose (16 values) ----
    #pragma unroll
    for (int k = 0; k < 16; ++k) {
        float x = vals[k];
        x += __shfl_xor(x, 8, 64);
        x += __shfl_xor(x, 4, 64);
        x += __shfl_xor(x, 2, 64);
        x += __shfl_xor(x, 1, 64);
        vals[k] = x;
    }
    const int g = tid >> 4, k16 = tid & 15;
    float myv = vals[0];
    #pragma unroll
    for (int k = 1; k < 16; ++k) if (k16 == k) myv = vals[k];   // static-index select
    red[g][k16] = myv;
    __syncthreads();

    if (tid < 16) {
        const int k = tid;
        float s = 0.f;
        #pragma unroll
        for (int g2 = 0; g2 < 16; ++g2) s += red[g2][k];
        int target;
        if (k < 13)       target = ACC_SUM + b * 13 + k;
        else if (k == 13) target = ACC_SSQ + b;
        else if (k == 14) target = ACC_GRAD;
        else              target = ACC_MASS;
        const int bank = (b * NWGX + blockIdx.x) & (NBANK - 1);
        atomicAdd(&ws[WS_ACC + bank * BANKSTRIDE + target], s);
    }
}

// ---------------- finalize: sum banks, apply formulas ----------------
__global__ void pl_finalize_kernel(const float* __restrict__ ws, float* __restrict__ out) {
    __shared__ float tot[N_ACC];
    const int t = threadIdx.x;
    if (t < N_ACC) {
        float s = 0.f;
        for (int bk = 0; bk < NBANK; ++bk) s += ws[WS_ACC + bk * BANKSTRIDE + t];
        tot[t] = s;
    }
    __syncthreads();
    if (t == 0) {
        const float N = (float)SLICE;
        float s2 = 0.f;
        for (int s = 0; s < 2 * NLEV; ++s) s2 += tot[ACC_SUM + s] * tot[ACC_SUM + s];
        const float ssq = tot[ACC_SSQ + 0] + tot[ACC_SSQ + 1];
        float vmean = (ssq - s2 / N) / (N - 1.0f) * (1.0f / (2.0f * NLEV));
        float gmean = tot[ACC_GRAD] / (float)(NBATCH * NLEV * SLICE);
        float mmean = tot[ACC_MASS] / (float)(NBATCH * SLICE);
        out[0] = vmean + 0.1f * gmean + mmean;          // spectra_loss statically 0
    }
}

extern "C" void kernel_launch(void* const* d_in, const int* in_sizes, int n_in,
                              void* d_out, int out_size, void* d_ws, size_t ws_size,
                              hipStream_t stream) {
    const float* u    = (const float*)d_in[0];
    const float* v    = (const float*)d_in[1];
    const float* plev = (const float*)d_in[2];
    float* ws  = (float*)d_ws;
    float* out = (float*)d_out;

    hipLaunchKernelGGL(pl_setup_kernel, dim3(1), dim3(1024), 0, stream, plev, ws);
    hipLaunchKernelGGL(pl_rc22p_kernel, dim3(NWGX, NBATCH), dim3(256), 0, stream, u, v, ws);
    hipLaunchKernelGGL(pl_finalize_kernel, dim3(1), dim3(64), 0, stream, ws, out);
}